// Round 5
// baseline (1655.137 us; speedup 1.0000x reference)
//
#include <hip/hip_runtime.h>
#include <cstddef>

#define BB 32
#define BH 8                  // b per block (quarter of 32)
#define NBQ 4                 // b-quarters
#define IC 2048
#define JD 16
#define NC 64
#define DD 32
#define ICHUNK 16
#define NIC (IC / ICHUNK)     // 128 i-chunks; grid = 128 x 4 = 512 (2/CU)

// ---------------------------------------------------------------- helpers ---
template<int CTRL>
__device__ __forceinline__ float dpp_mov_f(float v) {
  int x = __builtin_amdgcn_mov_dpp(__float_as_int(v), CTRL, 0xf, 0xf, true);
  return __int_as_float(x);
}
// sum over the 16 lanes of each row (rotate-reduce, VALU pipe, no LDS)
__device__ __forceinline__ float row16_sum(float v) {
  v += dpp_mov_f<0x121>(v);  // row_ror:1
  v += dpp_mov_f<0x122>(v);  // row_ror:2
  v += dpp_mov_f<0x124>(v);  // row_ror:4
  v += dpp_mov_f<0x128>(v);  // row_ror:8
  return v;
}

// ---------------------------------------------------------------- zero s ----
__global__ void caps_zero(float* __restrict__ s) {
  int t = blockIdx.x * 256 + threadIdx.x;
  s[t] = 0.0f;
}

// ------------------------------------------------------------- pass kernel --
// grid = 512: (128 i-chunks) x (4 b-quarters). block = 1024 (16 waves).
// 2 blocks/CU at 64 VGPR -> barriers/latency in one block hide under the other.
// wave w owns n {4w..4w+3}; lane l: n_loc=l>>4, dg=l&15 -> d {2dg,2dg+1}.
// Live set ~62 regs: acc 16 + wr 32 + quad temps 8 + addr -> fits 64, no spill.
// XCD pairing: blk = xcd + 8*slot (dispatch round-robin); the 4 b-quarters of
// one i-chunk are consecutive slots on the SAME XCD; their shared 2 MB
// W-footprint fits the 4 MB L2 -> W streamed from HBM ~once per pass.
// Mapping is bijective -> correctness never depends on physical XCD layout.
__global__ __launch_bounds__(1024, 8)
void caps_pass(const float* __restrict__ x, const float* __restrict__ W,
               const float* __restrict__ V, float* __restrict__ sOut,
               float* __restrict__ sPart, int r, int usePart)
{
  const int t    = threadIdx.x;
  const int w    = t >> 6;           // 0..15
  const int l    = t & 63;
  const int n    = (w << 2) | (l >> 4);
  const int d0   = (l & 15) << 1;    // 2 d's per thread
  const int blk  = blockIdx.x;
  const int xcd  = blk & 7;
  const int slot = blk >> 3;         // 0..63
  const int ic   = xcd * 16 + (slot >> 2);   // 0..127
  const int bq   = slot & 3;                 // b-quarter
  const int i0   = ic * ICHUNK;
  const int bbase = bq * BH;

  __shared__ float den[2][2][4];     // [ii-parity][quad][bb]

  float acc0[BH], acc1[BH];
#pragma unroll
  for (int b = 0; b < BH; ++b) { acc0[b] = 0.0f; acc1[b] = 0.0f; }

  for (int ii = 0; ii < ICHUNK; ++ii) {
    const int i = i0 + ii;
    const int p = ii & 1;
    // W[n, i, d0..d0+1, 0..15] : 32 f32 = 128 B contiguous per thread
    const float4* Wp = reinterpret_cast<const float4*>(
        W + (((size_t)n * IC + i) * DD + d0) * JD);
    float4 wr[8];
#pragma unroll
    for (int q = 0; q < 8; ++q) wr[q] = Wp[q];

    if (r == 0) {
      // c = 1/64 exactly (softmax of zeros): no logits, no barriers
#pragma unroll
      for (int bl = 0; bl < BH; ++bl) {
        const float* xp = x + ((size_t)(bbase + bl) * IC + i) * JD;  // uniform
        float u0 = 0.f, u1 = 0.f;
#pragma unroll
        for (int q = 0; q < 4; ++q) {
          float4 w0 = wr[q], w1 = wr[4 + q];
          float x0 = xp[4*q], x1 = xp[4*q+1], x2 = xp[4*q+2], x3 = xp[4*q+3];
          u0 += w0.x*x0 + w0.y*x1 + w0.z*x2 + w0.w*x3;
          u1 += w1.x*x0 + w1.y*x1 + w1.z*x2 + w1.w*x3;
        }
        acc0[bl] += u0 * 0.015625f;
        acc1[bl] += u1 * 0.015625f;
      }
    } else {
      if (t < 8) ((float*)den[p])[t] = 0.0f;    // zero both quad slots
      __syncthreads();
#pragma unroll
      for (int qd = 0; qd < 2; ++qd) {          // 2 quads of 4 b
        float p0a[4], p1a[4];                   // e*u, no separate e array
#pragma unroll
        for (int bb = 0; bb < 4; ++bb) {
          const int bl = qd * 4 + bb;
          const float* xp = x + ((size_t)(bbase + bl) * IC + i) * JD;
          float u0 = 0.f, u1 = 0.f;
#pragma unroll
          for (int q = 0; q < 4; ++q) {
            float4 w0 = wr[q], w1 = wr[4 + q];
            float x0 = xp[4*q], x1 = xp[4*q+1], x2 = xp[4*q+2], x3 = xp[4*q+3];
            u0 += w0.x*x0 + w0.y*x1 + w0.z*x2 + w0.w*x3;
            u1 += w1.x*x0 + w1.y*x1 + w1.z*x2 + w1.w*x3;
          }
          const float2 vv = *reinterpret_cast<const float2*>(
              V + ((size_t)(bbase + bl) * NC + n) * DD + d0);
          float lp = u0 * vv.x + u1 * vv.y;
          float logit = row16_sum(lp);          // uniform within 16-lane row
          // |logit| small (V squashed): exp safe w/o max-sub; identical to
          // the reference's max-subtracted softmax.
          float e = __expf(logit);
          p0a[bb] = e * u0;
          p1a[bb] = e * u1;
          float es = e + __shfl_xor(e, 16);     // 2 rows
          es += __shfl_xor(es, 32);             // all 4 rows of the wave
          if (l == 0) atomicAdd(&den[p][qd][bb], es);
        }
        __syncthreads();                        // den[p][qd] complete
#pragma unroll
        for (int bb = 0; bb < 4; ++bb) {
          const int bl = qd * 4 + bb;
          float rden = 1.0f / den[p][qd][bb];   // broadcast LDS read
          acc0[bl] += p0a[bb] * rden;
          acc1[bl] += p1a[bb] * rden;
        }
        // qd=1 atomics touch den[p][1] while qd=0 reads den[p][0]: disjoint.
        // Next ii zeroes den[p^1]: disjoint from this ii's reads. 3 bar/ii.
      }
    }
  }

  if (usePart) {
    // sPart pages: [(bq*NIC+ic)][bl][n][d] -> float2 stores, coalesced
#pragma unroll
    for (int bl = 0; bl < BH; ++bl) {
      float2 v2 = make_float2(acc0[bl], acc1[bl]);
      size_t off = (((size_t)(bq * NIC + ic) * BH + bl) * NC + n) * DD + d0;
      *reinterpret_cast<float2*>(sPart + off) = v2;
    }
  } else {
#pragma unroll
    for (int bl = 0; bl < BH; ++bl) {
      float* sp = sOut + ((size_t)(bbase + bl) * NC + n) * DD + d0;
      atomicAdd(sp, acc0[bl]);
      atomicAdd(sp + 1, acc1[bl]);
    }
  }
}

// ------------------------------------------------------- tree reduce L1/L2 --
// per b-quarter bq: pages [128 ic][4096 float4]; s_f4[bq*4096+q] = sum over ic.
__global__ void caps_reduce1(const float4* __restrict__ sPart,
                             float4* __restrict__ part2) {
  int blk = blockIdx.x;              // 512 = 4bq x 8pg x 16qb
  int bq = blk >> 7;
  int pg = (blk >> 4) & 7;
  int qb = blk & 15;
  int q  = qb * 256 + threadIdx.x;   // 0..4095
  float4 sum = make_float4(0.f, 0.f, 0.f, 0.f);
#pragma unroll 8
  for (int p = 0; p < 16; ++p) {
    float4 v = sPart[(size_t)(bq * NIC + pg * 16 + p) * 4096 + q];
    sum.x += v.x; sum.y += v.y; sum.z += v.z; sum.w += v.w;
  }
  part2[((size_t)bq * 8 + pg) * 4096 + q] = sum;
}
__global__ void caps_reduce2(const float4* __restrict__ part2,
                             float4* __restrict__ s) {
  int blk = blockIdx.x;              // 64 = 4bq x 16qb
  int bq = blk >> 4, qb = blk & 15;
  int q = qb * 256 + threadIdx.x;
  float4 sum = make_float4(0.f, 0.f, 0.f, 0.f);
#pragma unroll
  for (int pg = 0; pg < 8; ++pg) {
    float4 v = part2[((size_t)bq * 8 + pg) * 4096 + q];
    sum.x += v.x; sum.y += v.y; sum.z += v.z; sum.w += v.w;
  }
  s[(size_t)bq * 4096 + q] = sum;
}
__global__ void caps_reduceS(const float4* __restrict__ sPart,
                             float4* __restrict__ s) {
  int blk = blockIdx.x;              // 64 = 4bq x 16qb
  int bq = blk >> 4, qb = blk & 15;
  int q = qb * 256 + threadIdx.x;
  float4 sum = make_float4(0.f, 0.f, 0.f, 0.f);
#pragma unroll 8
  for (int p = 0; p < NIC; ++p) {
    float4 v = sPart[(size_t)(bq * NIC + p) * 4096 + q];
    sum.x += v.x; sum.y += v.y; sum.z += v.z; sum.w += v.w;
  }
  s[(size_t)bq * 4096 + q] = sum;
}

// ---------------------------------------------------------------- squash ----
// one (b,n) per 32-lane half-wave; V layout [b][n][d] (same as s).
__global__ void caps_squash(const float* __restrict__ s, float* __restrict__ V,
                            float* __restrict__ out, int mode)
{
  const int t = threadIdx.x;
  const int g = blockIdx.x * 8 + (t >> 5);   // b*64+n, grid 256
  const int d = t & 31;
  float v  = s[(size_t)g * DD + d];
  float s2 = v * v;
#pragma unroll
  for (int off = 16; off; off >>= 1) s2 += __shfl_xor(s2, off);  // 32 d's
  float scale = s2 / ((1.0f + s2) * sqrtf(s2 + 1e-7f));
  float vd = scale * v;
  if (mode == 2)      out[(size_t)g * DD + d] = vd;
  else if (mode == 0) V[(size_t)g * DD + d] = vd;
  else                V[(size_t)g * DD + d] += vd;
}

// ---------------------------------------------------------------------------
extern "C" void kernel_launch(void* const* d_in, const int* in_sizes, int n_in,
                              void* d_out, int out_size, void* d_ws, size_t ws_size,
                              hipStream_t stream) {
  const float* x = (const float*)d_in[0];
  const float* W = (const float*)d_in[1];
  float* out   = (float*)d_out;
  float* s     = (float*)d_ws;                       // 64K f32
  float* V     = s + 65536;                          // 64K f32 [b][n][d]
  float* sPart = V + 65536;                          // 512*16384 f32 = 33.5 MB
  float* part2 = sPart + 512ull * 16384;             // 32*16384 f32 = 2 MB

  const size_t need1 = (2ull * 65536 + 512ull * 16384) * 4;
  const size_t need2 = need1 + 32ull * 16384 * 4;
  const int usePart  = (ws_size >= need1) ? 1 : 0;
  const int useTwo   = (ws_size >= need2) ? 1 : 0;

  for (int r = 0; r < 3; ++r) {
    if (!usePart) caps_zero<<<256, 256, 0, stream>>>(s);
    caps_pass<<<512, 1024, 0, stream>>>(x, W, V, s, sPart, r, usePart);
    if (usePart) {
      if (useTwo) {
        caps_reduce1<<<512, 256, 0, stream>>>((const float4*)sPart, (float4*)part2);
        caps_reduce2<<<64, 256, 0, stream>>>((const float4*)part2, (float4*)s);
      } else {
        caps_reduceS<<<64, 256, 0, stream>>>((const float4*)sPart, (float4*)s);
      }
    }
    caps_squash<<<256, 256, 0, stream>>>(s, V, out, r == 2 ? 2 : (r == 0 ? 0 : 1));
  }
}

// Round 6
// 1045.246 us; speedup vs baseline: 1.5835x; 1.5835x over previous
//
#include <hip/hip_runtime.h>
#include <cstddef>

#define BB 32
#define BH 4                  // b per block
#define NBQ 8                 // b-groups
#define IC 2048
#define JD 16
#define NC 64
#define DD 32
#define ICHUNK 32
#define NIC (IC / ICHUNK)     // 64 i-chunks; grid = 64 x 8 = 512 (2/CU)

// ---------------------------------------------------------------- helpers ---
template<int CTRL>
__device__ __forceinline__ float dpp_mov_f(float v) {
  int x = __builtin_amdgcn_mov_dpp(__float_as_int(v), CTRL, 0xf, 0xf, true);
  return __int_as_float(x);
}
// sum over the 16 lanes of each row (rotate-reduce, VALU pipe, no LDS)
__device__ __forceinline__ float row16_sum(float v) {
  v += dpp_mov_f<0x121>(v);  // row_ror:1
  v += dpp_mov_f<0x122>(v);  // row_ror:2
  v += dpp_mov_f<0x124>(v);  // row_ror:4
  v += dpp_mov_f<0x128>(v);  // row_ror:8
  return v;
}

// ---------------------------------------------------------------- zero s ----
__global__ void caps_zero(float* __restrict__ s) {
  int t = blockIdx.x * 256 + threadIdx.x;
  s[t] = 0.0f;
}

// ------------------------------------------------------------- pass kernel --
// grid = 512: (64 i-chunks) x (8 b-groups of 4). block = 1024 (16 waves).
// Exactly 2 blocks/CU -> barriers/latency of one block hide under the other.
// wave w owns n {4w..4w+3}; lane l: n_loc=l>>4, dg=l&15 -> d {2dg,2dg+1}.
// Live set ~60 regs: wr 32 + acc 8 + quad temps 8 + addr ~12 -> fits the
// 64-VGPR clamp the RA picks for this shape (R2-R5 evidence) with NO spill.
// XCD pairing: blk = xcd + 8*slot; the 8 b-group blocks of one i-chunk are
// consecutive slots on the SAME XCD -> W chunk (4 MB) streamed from HBM ~once,
// other 7 readers hit that XCD's L2. Bijective -> correctness-independent.
// V is staged in LDS (this block's 4 b's = 32 KB) -> no global V in the loop.
__global__ __launch_bounds__(1024, 4)
void caps_pass(const float* __restrict__ x, const float* __restrict__ W,
               const float* __restrict__ V, float* __restrict__ sOut,
               float* __restrict__ sPart, int r, int usePart)
{
  const int t    = threadIdx.x;
  const int w    = t >> 6;           // 0..15
  const int l    = t & 63;
  const int n    = (w << 2) | (l >> 4);
  const int d0   = (l & 15) << 1;    // 2 d's per thread
  const int blk  = blockIdx.x;
  const int xcd  = blk & 7;
  const int slot = blk >> 3;         // 0..63
  const int ic   = xcd * 8 + (slot >> 3);    // 0..63
  const int bq   = slot & 7;                 // b-group
  const int i0   = ic * ICHUNK;
  const int bbase = bq * BH;

  __shared__ float den[2][BH];       // [ii-parity][bb]
  __shared__ float Vlds[BH * NC * DD];  // 32 KB: V[bbase..bbase+3][n][d]

  if (r != 0) {
    // stage V once: 8192 f32, contiguous from V + bbase*2048
    const float4* src = reinterpret_cast<const float4*>(V + (size_t)bbase * 2048);
    float4* dst = reinterpret_cast<float4*>(Vlds);
    dst[t]        = src[t];
    dst[t + 1024] = src[t + 1024];
    // first __syncthreads below covers this load before any Vlds read
  }

  float acc0[BH], acc1[BH];
#pragma unroll
  for (int b = 0; b < BH; ++b) { acc0[b] = 0.0f; acc1[b] = 0.0f; }

  for (int ii = 0; ii < ICHUNK; ++ii) {
    const int i = i0 + ii;
    const int p = ii & 1;
    // W[n, i, d0..d0+1, 0..15] : 32 f32 = 128 B contiguous per thread
    const float4* Wp = reinterpret_cast<const float4*>(
        W + (((size_t)n * IC + i) * DD + d0) * JD);
    float4 wr[8];
#pragma unroll
    for (int q = 0; q < 8; ++q) wr[q] = Wp[q];

    if (r == 0) {
      // c = 1/64 exactly (softmax of zeros): no logits, no barriers
#pragma unroll
      for (int bb = 0; bb < BH; ++bb) {
        const float* xp = x + ((size_t)(bbase + bb) * IC + i) * JD;  // uniform
        float u0 = 0.f, u1 = 0.f;
#pragma unroll
        for (int q = 0; q < 4; ++q) {
          float4 w0 = wr[q], w1 = wr[4 + q];
          float x0 = xp[4*q], x1 = xp[4*q+1], x2 = xp[4*q+2], x3 = xp[4*q+3];
          u0 += w0.x*x0 + w0.y*x1 + w0.z*x2 + w0.w*x3;
          u1 += w1.x*x0 + w1.y*x1 + w1.z*x2 + w1.w*x3;
        }
        acc0[bb] += u0 * 0.015625f;
        acc1[bb] += u1 * 0.015625f;
      }
    } else {
      if (t < BH) den[p][t] = 0.0f;
      __syncthreads();                        // den zero + (ii=0) Vlds ready
      float p0a[BH], p1a[BH];                 // e*u, carried across barrier
#pragma unroll
      for (int bb = 0; bb < BH; ++bb) {
        const float* xp = x + ((size_t)(bbase + bb) * IC + i) * JD;
        float u0 = 0.f, u1 = 0.f;
#pragma unroll
        for (int q = 0; q < 4; ++q) {
          float4 w0 = wr[q], w1 = wr[4 + q];
          float x0 = xp[4*q], x1 = xp[4*q+1], x2 = xp[4*q+2], x3 = xp[4*q+3];
          u0 += w0.x*x0 + w0.y*x1 + w0.z*x2 + w0.w*x3;
          u1 += w1.x*x0 + w1.y*x1 + w1.z*x2 + w1.w*x3;
        }
        const float2 vv = *reinterpret_cast<const float2*>(
            &Vlds[((size_t)bb * NC + n) * DD + d0]);
        float lp = u0 * vv.x + u1 * vv.y;
        float logit = row16_sum(lp);          // uniform within 16-lane row
        // |logit| small (V squashed): exp safe w/o max-sub; identical to
        // the reference's max-subtracted softmax.
        float e = __expf(logit);
        p0a[bb] = e * u0;
        p1a[bb] = e * u1;
        float es = e + __shfl_xor(e, 16);     // 2 rows
        es += __shfl_xor(es, 32);             // all 4 rows of the wave
        if (l == 0) atomicAdd(&den[p][bb], es);
      }
      __syncthreads();                        // den[p] complete
#pragma unroll
      for (int bb = 0; bb < BH; ++bb) {
        float rden = 1.0f / den[p][bb];       // broadcast LDS read
        acc0[bb] += p0a[bb] * rden;
        acc1[bb] += p1a[bb] * rden;
      }
      // next ii zeroes den[p^1] (pre-barrier) while stragglers read den[p]:
      // disjoint; den[p] is re-zeroed only at ii+2, after two barriers.
    }
  }

  if (usePart) {
    // sPart pages [bq*NIC+ic][bb][n][d] (8192 f32) -> float2 coalesced stores
#pragma unroll
    for (int bb = 0; bb < BH; ++bb) {
      float2 v2 = make_float2(acc0[bb], acc1[bb]);
      size_t off = (((size_t)(bq * NIC + ic) * BH + bb) * NC + n) * DD + d0;
      *reinterpret_cast<float2*>(sPart + off) = v2;
    }
  } else {
#pragma unroll
    for (int bb = 0; bb < BH; ++bb) {
      float* sp = sOut + ((size_t)(bbase + bb) * NC + n) * DD + d0;
      atomicAdd(sp, acc0[bb]);
      atomicAdd(sp + 1, acc1[bb]);
    }
  }
}

// ----------------------------------------------------------- tree reduce ----
// s_f4[q] = sum over 64 ic-pages of its b-group. q in [0,16384): bq = q>>11.
__global__ void caps_reduceS(const float4* __restrict__ sPart,
                             float4* __restrict__ s) {
  int q  = blockIdx.x * 256 + threadIdx.x;   // grid 64 x 256
  int bq = q >> 11, qq = q & 2047;
  float4 sum = make_float4(0.f, 0.f, 0.f, 0.f);
#pragma unroll 8
  for (int p = 0; p < NIC; ++p) {
    float4 v = sPart[(size_t)(bq * NIC + p) * 2048 + qq];
    sum.x += v.x; sum.y += v.y; sum.z += v.z; sum.w += v.w;
  }
  s[q] = sum;
}

// ---------------------------------------------------------------- squash ----
// one (b,n) per 32-lane half-wave; V layout [b][n][d] (same as s).
__global__ void caps_squash(const float* __restrict__ s, float* __restrict__ V,
                            float* __restrict__ out, int mode)
{
  const int t = threadIdx.x;
  const int g = blockIdx.x * 8 + (t >> 5);   // b*64+n, grid 256
  const int d = t & 31;
  float v  = s[(size_t)g * DD + d];
  float s2 = v * v;
#pragma unroll
  for (int off = 16; off; off >>= 1) s2 += __shfl_xor(s2, off);  // 32 d's
  float scale = s2 / ((1.0f + s2) * sqrtf(s2 + 1e-7f));
  float vd = scale * v;
  if (mode == 2)      out[(size_t)g * DD + d] = vd;
  else if (mode == 0) V[(size_t)g * DD + d] = vd;
  else                V[(size_t)g * DD + d] += vd;
}

// ---------------------------------------------------------------------------
extern "C" void kernel_launch(void* const* d_in, const int* in_sizes, int n_in,
                              void* d_out, int out_size, void* d_ws, size_t ws_size,
                              hipStream_t stream) {
  const float* x = (const float*)d_in[0];
  const float* W = (const float*)d_in[1];
  float* out   = (float*)d_out;
  float* s     = (float*)d_ws;                       // 64K f32
  float* V     = s + 65536;                          // 64K f32 [b][n][d]
  float* sPart = V + 65536;                          // 512*8192 f32 = 16.8 MB

  const size_t need1 = (2ull * 65536 + 512ull * 8192) * 4;
  const int usePart  = (ws_size >= need1) ? 1 : 0;

  for (int r = 0; r < 3; ++r) {
    if (!usePart) caps_zero<<<256, 256, 0, stream>>>(s);
    caps_pass<<<512, 1024, 0, stream>>>(x, W, V, s, sPart, r, usePart);
    if (usePart)
      caps_reduceS<<<64, 256, 0, stream>>>((const float4*)sPart, (float4*)s);
    caps_squash<<<256, 256, 0, stream>>>(s, V, out, r == 2 ? 2 : (r == 0 ? 0 : 1));
  }
}

// Round 7
// 761.526 us; speedup vs baseline: 2.1734x; 1.3726x over previous
//
#include <hip/hip_runtime.h>
#include <cstddef>

typedef short  bf16x8 __attribute__((ext_vector_type(8)));
typedef float  f32x16 __attribute__((ext_vector_type(16)));

#define BB 32
#define IC 2048
#define JD 16
#define NC 64
#define DD 32

// ---------------------------------------------------------------- helpers ---
__device__ __forceinline__ unsigned f2bf1(float f) {          // RNE f32->bf16
  unsigned u = __float_as_uint(f);
  return (u + 0x7FFFu + ((u >> 16) & 1u)) >> 16;
}
__device__ __forceinline__ unsigned pk2(float lo, float hi) { // 2 bf16 in u32
  return f2bf1(lo) | (f2bf1(hi) << 16);
}
__device__ __forceinline__ float bflo(unsigned v) { return __uint_as_float(v << 16); }
__device__ __forceinline__ float bfhi(unsigned v) { return __uint_as_float(v & 0xFFFF0000u); }

template<int CTRL>
__device__ __forceinline__ float dpp_mov_f(float v) {
  int x = __builtin_amdgcn_mov_dpp(__float_as_int(v), CTRL, 0xf, 0xf, true);
  return __int_as_float(x);
}
__device__ __forceinline__ float row16_sum(float v) {
  v += dpp_mov_f<0x121>(v);
  v += dpp_mov_f<0x122>(v);
  v += dpp_mov_f<0x124>(v);
  v += dpp_mov_f<0x128>(v);
  return v;
}

// =================================================== NEW MFMA-based path ====
// conv_w: W f32 [64][2048][32][16] -> bf16 same layout. 67.1M elems.
__global__ __launch_bounds__(256) void conv_w(const float4* __restrict__ Wf,
                                              uint4* __restrict__ Wb) {
  const size_t stride = (size_t)gridDim.x * 256;
  for (size_t g = blockIdx.x * 256 + threadIdx.x; g < 8388608ull; g += stride) {
    float4 a = Wf[2 * g], b = Wf[2 * g + 1];
    uint4 o;
    o.x = pk2(a.x, a.y); o.y = pk2(a.z, a.w);
    o.z = pk2(b.x, b.y); o.w = pk2(b.z, b.w);
    Wb[g] = o;
  }
}

// A-kernel: logits + softmax denominators. grid 1024 (i-pairs), 256 thr.
// wave w covers n in [16w,16w+16); per (n,i): u = MFMA(W-frag, x-frag),
// logit = V.u (+xor-32 half-sum), den[i][b] = sum_n exp(logit).
// MFMA 32x32x16 maps: A-row(d)=lane&31, B-col(b)=lane&31 (per C/D-verified
// layout); per-lane k-order is correctness-irrelevant (same bijection both
// operands => complete-sum reindex).
__global__ __launch_bounds__(256) void caps_logits(
    const float* __restrict__ x, const unsigned short* __restrict__ Wb,
    const unsigned short* __restrict__ Vb, float* __restrict__ den)
{
  const int t = threadIdx.x, w = t >> 6, l = t & 63;
  const int m = l & 31, h = l >> 5;      // m = A-row(d) on load, C-col(b) out
  const int i0 = blockIdx.x * 2;
  __shared__ __align__(16) unsigned short xl[2][32][16];   // x tile, bf16
  __shared__ float den4[4][32];
  {
    int g = t;                                  // 256 granules of 4 bf16
    int il = g >> 7, bb = (g >> 2) & 31, q4 = g & 3;
    const float4 xv = *reinterpret_cast<const float4*>(
        x + ((size_t)bb * IC + (i0 + il)) * JD + q4 * 4);
    unsigned* dst = reinterpret_cast<unsigned*>(&xl[il][bb][q4 * 4]);
    dst[0] = pk2(xv.x, xv.y);
    dst[1] = pk2(xv.z, xv.w);
  }
  __syncthreads();
  for (int il = 0; il < 2; ++il) {
    const int i = i0 + il;
    bf16x8 bfrag = *reinterpret_cast<const bf16x8*>(&xl[il][m][h * 8]);
    float pden = 0.f;
    for (int nn = 0; nn < 16; ++nn) {
      const int n = w * 16 + nn;
      bf16x8 afrag = *reinterpret_cast<const bf16x8*>(
          Wb + (((size_t)n * IC + i) * DD + m) * JD + h * 8);
      f32x16 u = __builtin_amdgcn_mfma_f32_32x32x16_bf16(
          afrag, bfrag, (f32x16)0.0f, 0, 0, 0);
      float partial = 0.f;
      const unsigned short* vrow = Vb + ((size_t)m * NC + n) * DD;
#pragma unroll
      for (int q = 0; q < 4; ++q) {          // d-chunk 2q+h -> d = 8q+4h..+3
        uint2 vv = *reinterpret_cast<const uint2*>(vrow + (2 * q + h) * 4);
        partial += bflo(vv.x) * u[4 * q + 0] + bfhi(vv.x) * u[4 * q + 1]
                 + bflo(vv.y) * u[4 * q + 2] + bfhi(vv.y) * u[4 * q + 3];
      }
      float logit = partial + __shfl_xor(partial, 32);
      pden += __expf(logit);   // |logit| small (V squashed); shift-invariant
    }
    if (h == 0) den4[w][m] = pden;
    __syncthreads();
    if (t < 32)
      den[(size_t)i * 32 + t] = den4[0][t] + den4[1][t] + den4[2][t] + den4[3][t];
    __syncthreads();                         // den4 reused next il
  }
}

// B-kernel: s-accumulation. grid 1024 = (256 i-chunks of 8) x (4 n-groups).
// wave w owns n in [nq*16+4w, +4); sacc[4][16] in regs (unrolled idx only).
__global__ __launch_bounds__(256) void caps_accum(
    const float* __restrict__ x, const unsigned short* __restrict__ Wb,
    const unsigned short* __restrict__ Vb, const float* __restrict__ den,
    float* __restrict__ sPart, int r)
{
  const int t = threadIdx.x, w = t >> 6, l = t & 63;
  const int m = l & 31, h = l >> 5;
  const int ic = blockIdx.x >> 2, nq = blockIdx.x & 3;
  const int i0 = ic * 8;
  const int n0 = nq * 16 + w * 4;
  __shared__ __align__(16) unsigned short xl[8][32][16];   // 8 KB
  for (int g = t; g < 1024; g += 256) {
    int il = g >> 7, bb = (g >> 2) & 31, q4 = g & 3;
    const float4 xv = *reinterpret_cast<const float4*>(
        x + ((size_t)bb * IC + (i0 + il)) * JD + q4 * 4);
    unsigned* dst = reinterpret_cast<unsigned*>(&xl[il][bb][q4 * 4]);
    dst[0] = pk2(xv.x, xv.y);
    dst[1] = pk2(xv.z, xv.w);
  }
  __syncthreads();
  f32x16 sacc[4];
#pragma unroll
  for (int nn = 0; nn < 4; ++nn) sacc[nn] = (f32x16)0.0f;

  for (int il = 0; il < 8; ++il) {
    const int i = i0 + il;
    bf16x8 bfrag = *reinterpret_cast<const bf16x8*>(&xl[il][m][h * 8]);
    float rden = 0.f;
    if (r) rden = 1.0f / den[(size_t)i * 32 + m];
#pragma unroll
    for (int nn = 0; nn < 4; ++nn) {
      const int n = n0 + nn;
      bf16x8 afrag = *reinterpret_cast<const bf16x8*>(
          Wb + (((size_t)n * IC + i) * DD + m) * JD + h * 8);
      f32x16 u = __builtin_amdgcn_mfma_f32_32x32x16_bf16(
          afrag, bfrag, (f32x16)0.0f, 0, 0, 0);
      float c;
      if (r == 0) {
        c = 0.015625f;                       // softmax of zeros = 1/64
      } else {
        float partial = 0.f;
        const unsigned short* vrow = Vb + ((size_t)m * NC + n) * DD;
#pragma unroll
        for (int q = 0; q < 4; ++q) {
          uint2 vv = *reinterpret_cast<const uint2*>(vrow + (2 * q + h) * 4);
          partial += bflo(vv.x) * u[4 * q + 0] + bfhi(vv.x) * u[4 * q + 1]
                   + bflo(vv.y) * u[4 * q + 2] + bfhi(vv.y) * u[4 * q + 3];
        }
        float logit = partial + __shfl_xor(partial, 32);
        c = __expf(logit) * rden;
      }
#pragma unroll
      for (int k = 0; k < 16; ++k) sacc[nn][k] += c * u[k];
    }
  }
  // sPart page ic: [n][dchunk(=2q+h)][b][4] f32, 65536 f32/page
  float* page = sPart + (size_t)ic * 65536;
#pragma unroll
  for (int nn = 0; nn < 4; ++nn) {
    const int n = n0 + nn;
#pragma unroll
    for (int q = 0; q < 4; ++q) {
      float4 v = make_float4(sacc[nn][4 * q + 0], sacc[nn][4 * q + 1],
                             sacc[nn][4 * q + 2], sacc[nn][4 * q + 3]);
      *reinterpret_cast<float4*>(page + (((size_t)n * 8 + 2 * q + h) * 32 + m) * 4) = v;
    }
  }
}

// reduce 256 pages -> s[b][n][d]
__global__ __launch_bounds__(256) void caps_reduce(const float4* __restrict__ sPart,
                                                   float* __restrict__ s) {
  int fid = blockIdx.x * 256 + threadIdx.x;        // 0..16383 float4s
  int n = fid >> 8, dc = (fid >> 5) & 7, b = fid & 31;
  float4 a = make_float4(0.f, 0.f, 0.f, 0.f);
#pragma unroll 8
  for (int p = 0; p < 256; ++p) {
    float4 v = sPart[(size_t)p * 16384 + fid];
    a.x += v.x; a.y += v.y; a.z += v.z; a.w += v.w;
  }
  *reinterpret_cast<float4*>(s + (((size_t)b * NC + n) * DD + dc * 4)) = a;
}

// squash; also emits Vb (bf16) for the next round's logits.
__global__ __launch_bounds__(256) void caps_squash(
    const float* __restrict__ s, float* __restrict__ V,
    unsigned short* __restrict__ Vb, float* __restrict__ out, int mode)
{
  const int t = threadIdx.x;
  const int g = blockIdx.x * 8 + (t >> 5);   // b*64+n
  const int d = t & 31;
  float v = s[(size_t)g * DD + d];
  float s2 = v * v;
#pragma unroll
  for (int off = 16; off; off >>= 1) s2 += __shfl_xor(s2, off);
  float scale = s2 / ((1.0f + s2) * sqrtf(s2 + 1e-7f));
  float vd = scale * v;
  if (mode == 2) {
    out[(size_t)g * DD + d] = vd;
  } else {
    float nv = (mode == 0) ? vd : V[(size_t)g * DD + d] + vd;
    V[(size_t)g * DD + d] = nv;
    Vb[(size_t)g * DD + d] = (unsigned short)f2bf1(nv);
  }
}

// ============================== fallback: R6 f32 path (ws too small) ========
__global__ void fb_zero(float* __restrict__ s) {
  s[blockIdx.x * 256 + threadIdx.x] = 0.0f;
}
__global__ __launch_bounds__(1024, 4)
void fb_pass(const float* __restrict__ x, const float* __restrict__ W,
             const float* __restrict__ V, float* __restrict__ sOut,
             float* __restrict__ sPart, int r, int usePart)
{
  const int t = threadIdx.x, w = t >> 6, l = t & 63;
  const int n = (w << 2) | (l >> 4);
  const int d0 = (l & 15) << 1;
  const int blk = blockIdx.x, xcd = blk & 7, slot = blk >> 3;
  const int ic = xcd * 8 + (slot >> 3), bq = slot & 7;
  const int i0 = ic * 32, bbase = bq * 4;
  __shared__ float den[2][4];
  __shared__ float Vlds[4 * NC * DD];
  if (r != 0) {
    const float4* src = reinterpret_cast<const float4*>(V + (size_t)bbase * 2048);
    float4* dst = reinterpret_cast<float4*>(Vlds);
    dst[t] = src[t]; dst[t + 1024] = src[t + 1024];
  }
  float acc0[4], acc1[4];
#pragma unroll
  for (int b = 0; b < 4; ++b) { acc0[b] = 0.f; acc1[b] = 0.f; }
  for (int ii = 0; ii < 32; ++ii) {
    const int i = i0 + ii, p = ii & 1;
    const float4* Wp = reinterpret_cast<const float4*>(
        W + (((size_t)n * IC + i) * DD + d0) * JD);
    float4 wr[8];
#pragma unroll
    for (int q = 0; q < 8; ++q) wr[q] = Wp[q];
    if (r == 0) {
#pragma unroll
      for (int bb = 0; bb < 4; ++bb) {
        const float* xp = x + ((size_t)(bbase + bb) * IC + i) * JD;
        float u0 = 0.f, u1 = 0.f;
#pragma unroll
        for (int q = 0; q < 4; ++q) {
          float4 w0 = wr[q], w1 = wr[4 + q];
          float x0 = xp[4*q], x1 = xp[4*q+1], x2 = xp[4*q+2], x3 = xp[4*q+3];
          u0 += w0.x*x0 + w0.y*x1 + w0.z*x2 + w0.w*x3;
          u1 += w1.x*x0 + w1.y*x1 + w1.z*x2 + w1.w*x3;
        }
        acc0[bb] += u0 * 0.015625f; acc1[bb] += u1 * 0.015625f;
      }
    } else {
      if (t < 4) den[p][t] = 0.0f;
      __syncthreads();
      float p0a[4], p1a[4];
#pragma unroll
      for (int bb = 0; bb < 4; ++bb) {
        const float* xp = x + ((size_t)(bbase + bb) * IC + i) * JD;
        float u0 = 0.f, u1 = 0.f;
#pragma unroll
        for (int q = 0; q < 4; ++q) {
          float4 w0 = wr[q], w1 = wr[4 + q];
          float x0 = xp[4*q], x1 = xp[4*q+1], x2 = xp[4*q+2], x3 = xp[4*q+3];
          u0 += w0.x*x0 + w0.y*x1 + w0.z*x2 + w0.w*x3;
          u1 += w1.x*x0 + w1.y*x1 + w1.z*x2 + w1.w*x3;
        }
        const float2 vv = *reinterpret_cast<const float2*>(
            &Vlds[((size_t)bb * NC + n) * DD + d0]);
        float lp = u0 * vv.x + u1 * vv.y;
        float logit = row16_sum(lp);
        float e = __expf(logit);
        p0a[bb] = e * u0; p1a[bb] = e * u1;
        float es = e + __shfl_xor(e, 16);
        es += __shfl_xor(es, 32);
        if (l == 0) atomicAdd(&den[p][bb], es);
      }
      __syncthreads();
#pragma unroll
      for (int bb = 0; bb < 4; ++bb) {
        float rd = 1.0f / den[p][bb];
        acc0[bb] += p0a[bb] * rd; acc1[bb] += p1a[bb] * rd;
      }
    }
  }
  if (usePart) {
#pragma unroll
    for (int bb = 0; bb < 4; ++bb) {
      float2 v2 = make_float2(acc0[bb], acc1[bb]);
      size_t off = (((size_t)(bq * 64 + ic) * 4 + bb) * NC + n) * DD + d0;
      *reinterpret_cast<float2*>(sPart + off) = v2;
    }
  } else {
#pragma unroll
    for (int bb = 0; bb < 4; ++bb) {
      float* sp = sOut + ((size_t)(bbase + bb) * NC + n) * DD + d0;
      atomicAdd(sp, acc0[bb]); atomicAdd(sp + 1, acc1[bb]);
    }
  }
}
__global__ void fb_reduceS(const float4* __restrict__ sPart, float4* __restrict__ s) {
  int q = blockIdx.x * 256 + threadIdx.x;
  int bq = q >> 11, qq = q & 2047;
  float4 sum = make_float4(0.f, 0.f, 0.f, 0.f);
#pragma unroll 8
  for (int p = 0; p < 64; ++p) {
    float4 v = sPart[(size_t)(bq * 64 + p) * 2048 + qq];
    sum.x += v.x; sum.y += v.y; sum.z += v.z; sum.w += v.w;
  }
  s[q] = sum;
}
__global__ void fb_squash(const float* __restrict__ s, float* __restrict__ V,
                          float* __restrict__ out, int mode)
{
  const int t = threadIdx.x;
  const int g = blockIdx.x * 8 + (t >> 5);
  const int d = t & 31;
  float v = s[(size_t)g * DD + d];
  float s2 = v * v;
#pragma unroll
  for (int off = 16; off; off >>= 1) s2 += __shfl_xor(s2, off);
  float scale = s2 / ((1.0f + s2) * sqrtf(s2 + 1e-7f));
  float vd = scale * v;
  if (mode == 2)      out[(size_t)g * DD + d] = vd;
  else if (mode == 0) V[(size_t)g * DD + d] = vd;
  else                V[(size_t)g * DD + d] += vd;
}

// ---------------------------------------------------------------------------
extern "C" void kernel_launch(void* const* d_in, const int* in_sizes, int n_in,
                              void* d_out, int out_size, void* d_ws, size_t ws_size,
                              hipStream_t stream) {
  const float* x = (const float*)d_in[0];
  const float* W = (const float*)d_in[1];
  float* out = (float*)d_out;
  char* ws = (char*)d_ws;
  const size_t NEED_NEW = 202244096ull;     // Wb + sPart + s + V + Vb + den

  if (ws_size >= NEED_NEW) {
    unsigned short* Wb = (unsigned short*)ws;                  // 134217728 B
    float* sPart       = (float*)(ws + 134217728);             //  67108864 B
    float* s           = (float*)(ws + 201326592);             //    262144 B
    float* V           = (float*)(ws + 201588736);             //    262144 B
    unsigned short* Vb = (unsigned short*)(ws + 201850880);    //    131072 B
    float* den         = (float*)(ws + 201981952);             //    262144 B
    conv_w<<<4096, 256, 0, stream>>>((const float4*)W, (uint4*)Wb);
    for (int r = 0; r < 3; ++r) {
      if (r) caps_logits<<<1024, 256, 0, stream>>>(x, Wb, Vb, den);
      caps_accum<<<1024, 256, 0, stream>>>(x, Wb, Vb, den, sPart, r);
      caps_reduce<<<64, 256, 0, stream>>>((const float4*)sPart, s);
      caps_squash<<<256, 256, 0, stream>>>(s, V, Vb, out,
                                           r == 2 ? 2 : (r == 0 ? 0 : 1));
    }
  } else {
    float* s     = (float*)ws;
    float* V     = s + 65536;
    float* sPart = V + 65536;
    const size_t need1 = (2ull * 65536 + 512ull * 8192) * 4;
    const int usePart = (ws_size >= need1) ? 1 : 0;
    for (int r = 0; r < 3; ++r) {
      if (!usePart) fb_zero<<<256, 256, 0, stream>>>(s);
      fb_pass<<<512, 1024, 0, stream>>>(x, W, V, s, sPart, r, usePart);
      if (usePart)
        fb_reduceS<<<64, 256, 0, stream>>>((const float4*)sPart, (float4*)s);
      fb_squash<<<256, 256, 0, stream>>>(s, V, out, r == 2 ? 2 : (r == 0 ? 0 : 1));
    }
  }
}

// Round 8
// 395.392 us; speedup vs baseline: 4.1861x; 1.9260x over previous
//
#include <hip/hip_runtime.h>
#include <cstddef>

typedef short  bf16x8 __attribute__((ext_vector_type(8)));
typedef float  f32x16 __attribute__((ext_vector_type(16)));

#define BB 32
#define IC 2048
#define JD 16
#define NC 64
#define DD 32
#define ICH 16                 // i per accum block
#define NICP (IC / ICH)        // 128 sPart pages

// ---------------------------------------------------------------- helpers ---
__device__ __forceinline__ unsigned f2bf1(float f) {          // RNE f32->bf16
  unsigned u = __float_as_uint(f);
  return (u + 0x7FFFu + ((u >> 16) & 1u)) >> 16;
}
__device__ __forceinline__ unsigned pk2(float lo, float hi) { // 2 bf16 in u32
  return f2bf1(lo) | (f2bf1(hi) << 16);
}
__device__ __forceinline__ float bflo(unsigned v) { return __uint_as_float(v << 16); }
__device__ __forceinline__ float bfhi(unsigned v) { return __uint_as_float(v & 0xFFFF0000u); }

template<int CTRL>
__device__ __forceinline__ float dpp_mov_f(float v) {
  int x = __builtin_amdgcn_mov_dpp(__float_as_int(v), CTRL, 0xf, 0xf, true);
  return __int_as_float(x);
}
__device__ __forceinline__ float row16_sum(float v) {
  v += dpp_mov_f<0x121>(v);
  v += dpp_mov_f<0x122>(v);
  v += dpp_mov_f<0x124>(v);
  v += dpp_mov_f<0x128>(v);
  return v;
}

// ========================================================= MFMA path ========
// Shared x-staging: xl[il][b][j] bf16 (pk2 of f32 x) — identical packing in
// all kernels so u is bit-identical between logits and accum.

// accum r0: c = 1/64 exactly -> sacc = chain of MFMAs, scale at store.
// ALSO converts W f32 -> Wb bf16 (each (n,i,lane) element owned by exactly
// one wave across the grid -> converted exactly once).
__global__ __launch_bounds__(256, 4) void caps_accum0(
    const float* __restrict__ x, const float* __restrict__ Wf,
    unsigned short* __restrict__ Wb, float* __restrict__ sPart)
{
  const int t = threadIdx.x, w = t >> 6, l = t & 63;
  const int m = l & 31, h = l >> 5;
  const int ic = blockIdx.x >> 3, nq = blockIdx.x & 7;
  const int i0 = ic * ICH;
  const int n0 = nq * 8 + w * 2;
  __shared__ __align__(16) unsigned short xl[ICH][32][16];   // 16 KB
  for (int g = t; g < 2048; g += 256) {          // granules of 4 bf16
    int il = g >> 7, bb = (g >> 2) & 31, q4 = g & 3;
    const float4 xv = *reinterpret_cast<const float4*>(
        x + ((size_t)bb * IC + (i0 + il)) * JD + q4 * 4);
    unsigned* dst = reinterpret_cast<unsigned*>(&xl[il][bb][q4 * 4]);
    dst[0] = pk2(xv.x, xv.y);
    dst[1] = pk2(xv.z, xv.w);
  }
  __syncthreads();
  f32x16 sacc0 = (f32x16)0.0f, sacc1 = (f32x16)0.0f;
  for (int il = 0; il < ICH; ++il) {
    const int i = i0 + il;
    bf16x8 bfrag = *reinterpret_cast<const bf16x8*>(&xl[il][m][h * 8]);
    size_t off0 = (((size_t)n0 * IC + i) * DD + m) * JD + h * 8;
    size_t off1 = ((((size_t)n0 + 1) * IC + i) * DD + m) * JD + h * 8;
    float4 a0 = *reinterpret_cast<const float4*>(Wf + off0);
    float4 a1 = *reinterpret_cast<const float4*>(Wf + off0 + 4);
    float4 b0 = *reinterpret_cast<const float4*>(Wf + off1);
    float4 b1 = *reinterpret_cast<const float4*>(Wf + off1 + 4);
    uint4 pA, pB;
    pA.x = pk2(a0.x, a0.y); pA.y = pk2(a0.z, a0.w);
    pA.z = pk2(a1.x, a1.y); pA.w = pk2(a1.z, a1.w);
    pB.x = pk2(b0.x, b0.y); pB.y = pk2(b0.z, b0.w);
    pB.z = pk2(b1.x, b1.y); pB.w = pk2(b1.z, b1.w);
    *reinterpret_cast<uint4*>(Wb + off0) = pA;
    *reinterpret_cast<uint4*>(Wb + off1) = pB;
    bf16x8 af0 = *reinterpret_cast<bf16x8*>(&pA);
    bf16x8 af1 = *reinterpret_cast<bf16x8*>(&pB);
    sacc0 = __builtin_amdgcn_mfma_f32_32x32x16_bf16(af0, bfrag, sacc0, 0, 0, 0);
    sacc1 = __builtin_amdgcn_mfma_f32_32x32x16_bf16(af1, bfrag, sacc1, 0, 0, 0);
  }
  float* page = sPart + (size_t)ic * 65536;      // [n][dchunk][b][4]
#pragma unroll
  for (int q = 0; q < 4; ++q) {
    float4 v0 = make_float4(sacc0[4*q]*0.015625f, sacc0[4*q+1]*0.015625f,
                            sacc0[4*q+2]*0.015625f, sacc0[4*q+3]*0.015625f);
    float4 v1 = make_float4(sacc1[4*q]*0.015625f, sacc1[4*q+1]*0.015625f,
                            sacc1[4*q+2]*0.015625f, sacc1[4*q+3]*0.015625f);
    *reinterpret_cast<float4*>(page + (((size_t)n0*8 + 2*q+h)*32 + m)*4) = v0;
    *reinterpret_cast<float4*>(page + ((((size_t)n0+1)*8 + 2*q+h)*32 + m)*4) = v1;
  }
}

// logits (r>=1): per i, all 64 n; writes C[i][n][b] = e/den.
__global__ __launch_bounds__(256) void caps_logits(
    const float* __restrict__ x, const unsigned short* __restrict__ Wb,
    const unsigned short* __restrict__ Vb, float* __restrict__ C)
{
  const int t = threadIdx.x, w = t >> 6, l = t & 63;
  const int m = l & 31, h = l >> 5;
  const int i = blockIdx.x;                      // grid 2048
  __shared__ __align__(16) unsigned short xl[32][16];
  __shared__ float den4[4][32];
  __shared__ float denf[32];
  if (t < 128) {
    int bb = t >> 2, q4 = t & 3;
    const float4 xv = *reinterpret_cast<const float4*>(
        x + ((size_t)bb * IC + i) * JD + q4 * 4);
    unsigned* dst = reinterpret_cast<unsigned*>(&xl[bb][q4 * 4]);
    dst[0] = pk2(xv.x, xv.y);
    dst[1] = pk2(xv.z, xv.w);
  }
  __syncthreads();
  bf16x8 bfrag = *reinterpret_cast<const bf16x8*>(&xl[m][h * 8]);
  float e[16];
  float pden = 0.f;
#pragma unroll
  for (int nn = 0; nn < 16; ++nn) {
    const int n = w * 16 + nn;
    bf16x8 afrag = *reinterpret_cast<const bf16x8*>(
        Wb + (((size_t)n * IC + i) * DD + m) * JD + h * 8);
    f32x16 u = __builtin_amdgcn_mfma_f32_32x32x16_bf16(
        afrag, bfrag, (f32x16)0.0f, 0, 0, 0);
    float partial = 0.f;
    const unsigned short* vrow = Vb + ((size_t)m * NC + n) * DD;
#pragma unroll
    for (int q = 0; q < 4; ++q) {                // d-chunk 2q+h
      uint2 vv = *reinterpret_cast<const uint2*>(vrow + (2 * q + h) * 4);
      partial += bflo(vv.x) * u[4*q+0] + bfhi(vv.x) * u[4*q+1]
               + bflo(vv.y) * u[4*q+2] + bfhi(vv.y) * u[4*q+3];
    }
    float logit = partial + __shfl_xor(partial, 32);
    // |logit| small (V squashed): exp safe w/o max-sub; shift-invariant.
    e[nn] = __expf(logit);
    pden += e[nn];
  }
  if (h == 0) den4[w][m] = pden;
  __syncthreads();
  if (t < 32) denf[t] = 1.0f / (den4[0][t] + den4[1][t] + den4[2][t] + den4[3][t]);
  __syncthreads();
  if (h == 0) {
    float rden = denf[m];
    float* crow = C + ((size_t)i * NC + w * 16) * 32 + m;
#pragma unroll
    for (int nn = 0; nn < 16; ++nn) crow[nn * 32] = e[nn] * rden;
  }
}

// accum r1/r2: weighted GEMM, c loaded from C. Same numerics as R7.
__global__ __launch_bounds__(256, 4) void caps_accum12(
    const float* __restrict__ x, const unsigned short* __restrict__ Wb,
    const float* __restrict__ C, float* __restrict__ sPart)
{
  const int t = threadIdx.x, w = t >> 6, l = t & 63;
  const int m = l & 31, h = l >> 5;
  const int ic = blockIdx.x >> 3, nq = blockIdx.x & 7;
  const int i0 = ic * ICH;
  const int n0 = nq * 8 + w * 2;
  __shared__ __align__(16) unsigned short xl[ICH][32][16];   // 16 KB
  for (int g = t; g < 2048; g += 256) {
    int il = g >> 7, bb = (g >> 2) & 31, q4 = g & 3;
    const float4 xv = *reinterpret_cast<const float4*>(
        x + ((size_t)bb * IC + (i0 + il)) * JD + q4 * 4);
    unsigned* dst = reinterpret_cast<unsigned*>(&xl[il][bb][q4 * 4]);
    dst[0] = pk2(xv.x, xv.y);
    dst[1] = pk2(xv.z, xv.w);
  }
  __syncthreads();
  f32x16 sacc0 = (f32x16)0.0f, sacc1 = (f32x16)0.0f;
  for (int il = 0; il < ICH; ++il) {
    const int i = i0 + il;
    bf16x8 bfrag = *reinterpret_cast<const bf16x8*>(&xl[il][m][h * 8]);
    float c0 = C[((size_t)i * NC + n0) * 32 + m];
    float c1 = C[((size_t)i * NC + n0 + 1) * 32 + m];
    bf16x8 af0 = *reinterpret_cast<const bf16x8*>(
        Wb + (((size_t)n0 * IC + i) * DD + m) * JD + h * 8);
    bf16x8 af1 = *reinterpret_cast<const bf16x8*>(
        Wb + ((((size_t)n0 + 1) * IC + i) * DD + m) * JD + h * 8);
    f32x16 u0 = __builtin_amdgcn_mfma_f32_32x32x16_bf16(
        af0, bfrag, (f32x16)0.0f, 0, 0, 0);
    f32x16 u1 = __builtin_amdgcn_mfma_f32_32x32x16_bf16(
        af1, bfrag, (f32x16)0.0f, 0, 0, 0);
#pragma unroll
    for (int k = 0; k < 16; ++k) {
      sacc0[k] += c0 * u0[k];
      sacc1[k] += c1 * u1[k];
    }
  }
  float* page = sPart + (size_t)ic * 65536;
#pragma unroll
  for (int q = 0; q < 4; ++q) {
    float4 v0 = make_float4(sacc0[4*q], sacc0[4*q+1], sacc0[4*q+2], sacc0[4*q+3]);
    float4 v1 = make_float4(sacc1[4*q], sacc1[4*q+1], sacc1[4*q+2], sacc1[4*q+3]);
    *reinterpret_cast<float4*>(page + (((size_t)n0*8 + 2*q+h)*32 + m)*4) = v0;
    *reinterpret_cast<float4*>(page + ((((size_t)n0+1)*8 + 2*q+h)*32 + m)*4) = v1;
  }
}

// 2-level reduce over 128 pages
__global__ __launch_bounds__(256) void caps_reduce1(
    const float4* __restrict__ sPart, float4* __restrict__ part2) {
  int blk = blockIdx.x;              // 256 = 4 pg x 64 fb
  int pg = blk >> 6, fb = blk & 63;
  int fid = fb * 256 + threadIdx.x;
  float4 a = make_float4(0.f, 0.f, 0.f, 0.f);
#pragma unroll 8
  for (int p = 0; p < 32; ++p) {
    float4 v = sPart[(size_t)(pg * 32 + p) * 16384 + fid];
    a.x += v.x; a.y += v.y; a.z += v.z; a.w += v.w;
  }
  part2[(size_t)pg * 16384 + fid] = a;
}
__global__ __launch_bounds__(256) void caps_reduce2(
    const float4* __restrict__ part2, float* __restrict__ s) {
  int fid = blockIdx.x * 256 + threadIdx.x;      // 0..16383
  int n = fid >> 8, dc = (fid >> 5) & 7, b = fid & 31;
  float4 a = make_float4(0.f, 0.f, 0.f, 0.f);
#pragma unroll
  for (int pg = 0; pg < 4; ++pg) {
    float4 v = part2[(size_t)pg * 16384 + fid];
    a.x += v.x; a.y += v.y; a.z += v.z; a.w += v.w;
  }
  *reinterpret_cast<float4*>(s + (((size_t)b * NC + n) * DD + dc * 4)) = a;
}

// squash; also emits Vb (bf16) for the next round's logits.
__global__ __launch_bounds__(256) void caps_squash(
    const float* __restrict__ s, float* __restrict__ V,
    unsigned short* __restrict__ Vb, float* __restrict__ out, int mode)
{
  const int t = threadIdx.x;
  const int g = blockIdx.x * 8 + (t >> 5);   // b*64+n
  const int d = t & 31;
  float v = s[(size_t)g * DD + d];
  float s2 = v * v;
#pragma unroll
  for (int off = 16; off; off >>= 1) s2 += __shfl_xor(s2, off);
  float scale = s2 / ((1.0f + s2) * sqrtf(s2 + 1e-7f));
  float vd = scale * v;
  if (mode == 2) {
    out[(size_t)g * DD + d] = vd;
  } else {
    float nv = (mode == 0) ? vd : V[(size_t)g * DD + d] + vd;
    V[(size_t)g * DD + d] = nv;
    Vb[(size_t)g * DD + d] = (unsigned short)f2bf1(nv);
  }
}

// ============================== fallback: R6 f32 path (ws too small) ========
__global__ void fb_zero(float* __restrict__ s) {
  s[blockIdx.x * 256 + threadIdx.x] = 0.0f;
}
__global__ __launch_bounds__(1024, 4)
void fb_pass(const float* __restrict__ x, const float* __restrict__ W,
             const float* __restrict__ V, float* __restrict__ sOut,
             float* __restrict__ sPart, int r, int usePart)
{
  const int t = threadIdx.x, w = t >> 6, l = t & 63;
  const int n = (w << 2) | (l >> 4);
  const int d0 = (l & 15) << 1;
  const int blk = blockIdx.x, xcd = blk & 7, slot = blk >> 3;
  const int ic = xcd * 8 + (slot >> 3), bq = slot & 7;
  const int i0 = ic * 32, bbase = bq * 4;
  __shared__ float den[2][4];
  __shared__ float Vlds[4 * NC * DD];
  if (r != 0) {
    const float4* src = reinterpret_cast<const float4*>(V + (size_t)bbase * 2048);
    float4* dst = reinterpret_cast<float4*>(Vlds);
    dst[t] = src[t]; dst[t + 1024] = src[t + 1024];
  }
  float acc0[4], acc1[4];
#pragma unroll
  for (int b = 0; b < 4; ++b) { acc0[b] = 0.f; acc1[b] = 0.f; }
  for (int ii = 0; ii < 32; ++ii) {
    const int i = i0 + ii, p = ii & 1;
    const float4* Wp = reinterpret_cast<const float4*>(
        W + (((size_t)n * IC + i) * DD + d0) * JD);
    float4 wr[8];
#pragma unroll
    for (int q = 0; q < 8; ++q) wr[q] = Wp[q];
    if (r == 0) {
#pragma unroll
      for (int bb = 0; bb < 4; ++bb) {
        const float* xp = x + ((size_t)(bbase + bb) * IC + i) * JD;
        float u0 = 0.f, u1 = 0.f;
#pragma unroll
        for (int q = 0; q < 4; ++q) {
          float4 w0 = wr[q], w1 = wr[4 + q];
          float x0 = xp[4*q], x1 = xp[4*q+1], x2 = xp[4*q+2], x3 = xp[4*q+3];
          u0 += w0.x*x0 + w0.y*x1 + w0.z*x2 + w0.w*x3;
          u1 += w1.x*x0 + w1.y*x1 + w1.z*x2 + w1.w*x3;
        }
        acc0[bb] += u0 * 0.015625f; acc1[bb] += u1 * 0.015625f;
      }
    } else {
      if (t < 4) den[p][t] = 0.0f;
      __syncthreads();
      float p0a[4], p1a[4];
#pragma unroll
      for (int bb = 0; bb < 4; ++bb) {
        const float* xp = x + ((size_t)(bbase + bb) * IC + i) * JD;
        float u0 = 0.f, u1 = 0.f;
#pragma unroll
        for (int q = 0; q < 4; ++q) {
          float4 w0 = wr[q], w1 = wr[4 + q];
          float x0 = xp[4*q], x1 = xp[4*q+1], x2 = xp[4*q+2], x3 = xp[4*q+3];
          u0 += w0.x*x0 + w0.y*x1 + w0.z*x2 + w0.w*x3;
          u1 += w1.x*x0 + w1.y*x1 + w1.z*x2 + w1.w*x3;
        }
        const float2 vv = *reinterpret_cast<const float2*>(
            &Vlds[((size_t)bb * NC + n) * DD + d0]);
        float lp = u0 * vv.x + u1 * vv.y;
        float logit = row16_sum(lp);
        float e = __expf(logit);
        p0a[bb] = e * u0; p1a[bb] = e * u1;
        float es = e + __shfl_xor(e, 16);
        es += __shfl_xor(es, 32);
        if (l == 0) atomicAdd(&den[p][bb], es);
      }
      __syncthreads();
#pragma unroll
      for (int bb = 0; bb < 4; ++bb) {
        float rd = 1.0f / den[p][bb];
        acc0[bb] += p0a[bb] * rd; acc1[bb] += p1a[bb] * rd;
      }
    }
  }
  if (usePart) {
#pragma unroll
    for (int bb = 0; bb < 4; ++bb) {
      float2 v2 = make_float2(acc0[bb], acc1[bb]);
      size_t off = (((size_t)(bq * 64 + ic) * 4 + bb) * NC + n) * DD + d0;
      *reinterpret_cast<float2*>(sPart + off) = v2;
    }
  } else {
#pragma unroll
    for (int bb = 0; bb < 4; ++bb) {
      float* sp = sOut + ((size_t)(bbase + bb) * NC + n) * DD + d0;
      atomicAdd(sp, acc0[bb]); atomicAdd(sp + 1, acc1[bb]);
    }
  }
}
__global__ void fb_reduceS(const float4* __restrict__ sPart, float4* __restrict__ s) {
  int q = blockIdx.x * 256 + threadIdx.x;
  int bq = q >> 11, qq = q & 2047;
  float4 sum = make_float4(0.f, 0.f, 0.f, 0.f);
#pragma unroll 8
  for (int p = 0; p < 64; ++p) {
    float4 v = sPart[(size_t)(bq * 64 + p) * 2048 + qq];
    sum.x += v.x; sum.y += v.y; sum.z += v.z; sum.w += v.w;
  }
  s[q] = sum;
}
__global__ void fb_squash(const float* __restrict__ s, float* __restrict__ V,
                          float* __restrict__ out, int mode)
{
  const int t = threadIdx.x;
  const int g = blockIdx.x * 8 + (t >> 5);
  const int d = t & 31;
  float v = s[(size_t)g * DD + d];
  float s2 = v * v;
#pragma unroll
  for (int off = 16; off; off >>= 1) s2 += __shfl_xor(s2, off);
  float scale = s2 / ((1.0f + s2) * sqrtf(s2 + 1e-7f));
  float vd = scale * v;
  if (mode == 2)      out[(size_t)g * DD + d] = vd;
  else if (mode == 0) V[(size_t)g * DD + d] = vd;
  else                V[(size_t)g * DD + d] += vd;
}

// ---------------------------------------------------------------------------
extern "C" void kernel_launch(void* const* d_in, const int* in_sizes, int n_in,
                              void* d_out, int out_size, void* d_ws, size_t ws_size,
                              hipStream_t stream) {
  const float* x = (const float*)d_in[0];
  const float* W = (const float*)d_in[1];
  float* out = (float*)d_out;
  char* ws = (char*)d_ws;
  // Wb 134217728 | sPart 33554432 | C 16777216 | part2 1048576 | s 262144
  // V 262144 | Vb 131072  => total 186252032
  const size_t NEED_NEW = 186252032ull;

  if (ws_size >= NEED_NEW) {
    unsigned short* Wb = (unsigned short*)ws;
    float* sPart = (float*)(ws + 134217728);
    float* Cbuf  = (float*)(ws + 167772160);
    float* part2 = (float*)(ws + 184549376);
    float* s     = (float*)(ws + 185597952);
    float* V     = (float*)(ws + 185860096);
    unsigned short* Vb = (unsigned short*)(ws + 186122240);
    for (int r = 0; r < 3; ++r) {
      if (r == 0) {
        caps_accum0<<<1024, 256, 0, stream>>>(x, W, Wb, sPart);
      } else {
        caps_logits<<<2048, 256, 0, stream>>>(x, Wb, Vb, Cbuf);
        caps_accum12<<<1024, 256, 0, stream>>>(x, Wb, Cbuf, sPart);
      }
      caps_reduce1<<<256, 256, 0, stream>>>((const float4*)sPart, (float4*)part2);
      caps_reduce2<<<64, 256, 0, stream>>>((const float4*)part2, s);
      caps_squash<<<256, 256, 0, stream>>>(s, V, Vb, out,
                                           r == 2 ? 2 : (r == 0 ? 0 : 1));
    }
  } else {
    float* s     = (float*)ws;
    float* V     = s + 65536;
    float* sPart = V + 65536;
    const size_t need1 = (2ull * 65536 + 512ull * 8192) * 4;
    const int usePart = (ws_size >= need1) ? 1 : 0;
    for (int r = 0; r < 3; ++r) {
      if (!usePart) fb_zero<<<256, 256, 0, stream>>>(s);
      fb_pass<<<512, 1024, 0, stream>>>(x, W, V, s, sPart, r, usePart);
      if (usePart)
        fb_reduceS<<<64, 256, 0, stream>>>((const float4*)sPart, (float4*)s);
      fb_squash<<<256, 256, 0, stream>>>(s, V, out, r == 2 ? 2 : (r == 0 ? 0 : 1));
    }
  }
}